// Round 1
// baseline (481.034 us; speedup 1.0000x reference)
//
#include <hip/hip_runtime.h>

// y[n,m,:] = x[n,m,:] @ W[l(m)] * (1/sqrt(128))
// x: [100000, 16, 128] f32   W: [4, 128, 128] f32   y: [100000, 16, 128] f32
//
// Strategy: memory-bound (1.64 GB traffic, 260us floor @6.3TB/s). Use bf16
// MFMA (16x16x32) so compute (~26us) disappears under the memory stream.
// Block = 4 waves, tile = 128 n-rows x 128 d-cols at fixed m (one weight
// matrix per block). Weights pre-transposed+scaled to bf16 in d_ws so B
// fragments are contiguous 16B loads (L1/L2-resident).
//
// Correctness note on MFMA operand layout: A and B fragments are loaded with
// the SAME k->(lanegroup,elem) mapping, so the MFMA result is invariant to
// the instruction's actual internal K permutation (it pairs A-elem j with
// B-elem j per lane group). C/D layout: col=lane&15, row=(lane>>4)*4+reg
// (HW-verified, learn_hip m89).

typedef __bf16 bf16x8 __attribute__((ext_vector_type(8)));
typedef float f32x4 __attribute__((ext_vector_type(4)));
typedef unsigned short u16x8 __attribute__((ext_vector_type(8)));

#define N_NODES 100000
#define MCOMP 16
#define CIN 128
#define ROWSTRIDE (MCOMP * CIN)  // 2048 floats per node

// round-to-nearest-even f32 -> bf16 bits (inputs are finite gaussians; no NaN)
__device__ __forceinline__ unsigned short f2b(float f) {
    unsigned int u = __float_as_uint(f);
    unsigned int r = (u + 0x7fffu + ((u >> 16) & 1u)) >> 16;
    return (unsigned short)r;
}

// Wt[l][d][c] = W[l][c][d] * (1/sqrt(128)) as bf16 bits. 4*128*128*2B = 128KiB.
__global__ void prep_weights(const float* __restrict__ w,
                             unsigned short* __restrict__ wt) {
    int idx = blockIdx.x * blockDim.x + threadIdx.x;  // 0..65535
    int l = idx >> 14;
    int rem = idx & 16383;
    int d = rem >> 7;
    int c = rem & 127;
    const float pw = 0.08838834764831845f;  // 1/sqrt(128)
    float v = w[(l << 14) + (c << 7) + d] * pw;
    wt[idx] = f2b(v);
}

__global__ __launch_bounds__(256, 2) void linear_mfma(
        const float* __restrict__ x,
        const unsigned short* __restrict__ wt,
        float* __restrict__ y) {
    const int m = blockIdx.y;
    const int l = (m >= 9) ? 3 : (m >= 4) ? 2 : (m >= 1) ? 1 : 0;
    const int nbase = blockIdx.x * 128;
    const int wid = threadIdx.x >> 6;
    const int lane = threadIdx.x & 63;
    const int lr = lane & 15;   // A row-in-frag / B col / D col
    const int lk = lane >> 4;   // k lane-group

    const unsigned short* wl = wt + (l << 14);

    // this wave: rows [nbase + wid*32, +32), two 16-row A fragments
    int row0 = nbase + wid * 32 + lr;
    int row1 = row0 + 16;
    int rc0 = row0 < N_NODES ? row0 : N_NODES - 1;  // clamp loads in tail tile
    int rc1 = row1 < N_NODES ? row1 : N_NODES - 1;

    const float* xa0 = x + (size_t)rc0 * ROWSTRIDE + m * CIN + lk * 8;
    const float* xa1 = x + (size_t)rc1 * ROWSTRIDE + m * CIN + lk * 8;

    f32x4 acc[2][8];
#pragma unroll
    for (int i = 0; i < 2; ++i)
#pragma unroll
        for (int j = 0; j < 8; ++j)
            acc[i][j] = (f32x4){0.f, 0.f, 0.f, 0.f};

#pragma unroll
    for (int kk = 0; kk < 4; ++kk) {
        // A fragments: 32B/lane, 16 fully-consumed 128B lines per frag
        f32x4 a0lo = *reinterpret_cast<const f32x4*>(xa0 + kk * 32);
        f32x4 a0hi = *reinterpret_cast<const f32x4*>(xa0 + kk * 32 + 4);
        f32x4 a1lo = *reinterpret_cast<const f32x4*>(xa1 + kk * 32);
        f32x4 a1hi = *reinterpret_cast<const f32x4*>(xa1 + kk * 32 + 4);
        u16x8 ab0, ab1;
#pragma unroll
        for (int j = 0; j < 4; ++j) {
            ab0[j] = f2b(a0lo[j]);
            ab0[j + 4] = f2b(a0hi[j]);
            ab1[j] = f2b(a1lo[j]);
            ab1[j + 4] = f2b(a1hi[j]);
        }
        bf16x8 a0 = __builtin_bit_cast(bf16x8, ab0);
        bf16x8 a1 = __builtin_bit_cast(bf16x8, ab1);

#pragma unroll
        for (int nn = 0; nn < 8; ++nn) {
            // B frag: lane reads Wt[l][nn*16 + lr][kk*32 + lk*8 .. +8] (16B)
            u16x8 br = *reinterpret_cast<const u16x8*>(
                wl + (((nn * 16 + lr) << 7) + kk * 32 + lk * 8));
            bf16x8 b = __builtin_bit_cast(bf16x8, br);
            acc[0][nn] = __builtin_amdgcn_mfma_f32_16x16x32_bf16(a0, b, acc[0][nn], 0, 0, 0);
            acc[1][nn] = __builtin_amdgcn_mfma_f32_16x16x32_bf16(a1, b, acc[1][nn], 0, 0, 0);
        }
    }

    // Epilogue: D col = lane&15, row = (lane>>4)*4 + reg
#pragma unroll
    for (int mm = 0; mm < 2; ++mm) {
        int rbase = nbase + wid * 32 + mm * 16 + lk * 4;
#pragma unroll
        for (int r = 0; r < 4; ++r) {
            int row = rbase + r;
            if (row < N_NODES) {
                float* yp = y + (size_t)row * ROWSTRIDE + m * CIN + lr;
#pragma unroll
                for (int nn = 0; nn < 8; ++nn)
                    yp[nn * 16] = acc[mm][nn][r];
            }
        }
    }
}

extern "C" void kernel_launch(void* const* d_in, const int* in_sizes, int n_in,
                              void* d_out, int out_size, void* d_ws, size_t ws_size,
                              hipStream_t stream) {
    const float* x = (const float*)d_in[0];
    const float* w = (const float*)d_in[1];
    float* y = (float*)d_out;
    unsigned short* wt = (unsigned short*)d_ws;  // 128 KiB of scratch used

    prep_weights<<<256, 256, 0, stream>>>(w, wt);

    dim3 grid((N_NODES + 127) / 128, MCOMP);  // 782 x 16
    linear_mfma<<<grid, 256, 0, stream>>>(x, wt, y);
}